// Round 27
// baseline (212.170 us; speedup 1.0000x reference)
//
#include <hip/hip_runtime.h>

#define B_SZ 2048
#define D_IN 256
#define L_N 48
#define H_N 256
#define O_N 10
#define WROW 303      // D + L - 1
#define LEAF_N 12336  // L*(D+1)
#define KTRI 1176     // 48*49/2 packed lower-tri cols
#define KH2 1224      // KTRI + 48 offs cols
#define KPAD2 1280    // padded K (20 x 64)

using short8 = __attribute__((ext_vector_type(8))) short;
using f32x4  = __attribute__((ext_vector_type(4))) float;

__device__ inline void bf16_split(float v, unsigned short& h, unsigned short& l) {
  unsigned bits = __float_as_uint(v);
  h = (unsigned short)(bits >> 16);
  float hf = __uint_as_float(bits & 0xFFFF0000u);
  float r = v - hf;
  l = (unsigned short)(__float_as_uint(r) >> 16);
}
__device__ inline unsigned short bf16_hi(float v) {
  return (unsigned short)(__float_as_uint(v) >> 16);
}
__device__ __forceinline__ float lane_bcast(float v, int i) {
  return __uint_as_float(__builtin_amdgcn_readlane(__float_as_uint(v), i));
}

// ---------------------------------------------------------------------------
// seq body, TWO BATCHES PER WAVE; solve operands from a small LDS buffer
// (wh only, 9KB, staged once per block): wave-uniform ds_read broadcasts
// with STATIC addresses pipeline rows ahead (vs s_load per-use lgkmcnt
// drain ~94K cyc/wave). Branchy structure keeps live ranges short (the
// R14 spill came from branchless + all-rows-live, not LDS itself).
// ---------------------------------------------------------------------------
__device__ __forceinline__ void seq_wave2(int b0, int lane,
                                          const float* __restrict__ W,
                                          const float* __restrict__ WHL,
                                          const float* __restrict__ x,
                                          const float* __restrict__ bvec,
                                          unsigned short* __restrict__ Ch,
                                          unsigned short* __restrict__ Cl,
                                          float* __restrict__ mask_out) {
  const int b1 = b0 + 1;
  float P0 = 0.f, P1 = 0.f;
  if (lane < 48) {
    const float* xr0 = x + (size_t)b0 * D_IN;
    const float* xr1 = x + (size_t)b1 * D_IN;
    const float* wr = W + lane * WROW;
    float a0 = 0.f, a1 = 0.f, c0 = 0.f, c1 = 0.f;
#pragma unroll 4
    for (int d = 0; d < 256; d += 2) {
      float w0 = wr[d], w1 = wr[d + 1];  // shared per-lane loads
      a0 = fmaf(xr0[d], w0, a0);
      a1 = fmaf(xr0[d + 1], w1, a1);
      c0 = fmaf(xr1[d], w0, c0);
      c1 = fmaf(xr1[d + 1], w1, c1);
    }
    P0 = a0 + a1;
    P1 = c0 + c1;
  }

  float whr[47];
#pragma unroll
  for (int k = 0; k < 47; ++k)
    whr[k] = (lane < 48) ? W[lane * WROW + 256 + k] : 0.f;

  float bv = (lane < 48) ? bvec[lane] : 0.f;
  float Pb0 = P0 + bv, Pb1 = P1 + bv;

  float s0[48], s1[48];
  float accA0 = 0.f, accB0 = 0.f, accA1 = 0.f, accB1 = 0.f;
  float offs0 = 0.f, offs1 = 0.f;
  int dl0 = 0, dl1 = 0;
#pragma unroll
  for (int i = 0; i < 48; ++i) {
    float z0 = Pb0 + accA0, z1 = Pb1 + accA1;
    float u0 = P0 + accB0, u1 = P1 + accB1;
    float ai0 = fmaxf(z0, 0.f), ai1 = fmaxf(z1, 0.f);
    float oi0 = (z0 > 0.f) ? u0 : 0.f, oi1 = (z1 > 0.f) ? u1 : 0.f;
    if (lane == i) {
      dl0 = (z0 > 0.f) ? 1 : 0;
      dl1 = (z1 > 0.f) ? 1 : 0;
      offs0 = ai0 - oi0;
      offs1 = ai1 - oi1;
    }
    float ab0 = lane_bcast(ai0, i), ab1 = lane_bcast(ai1, i);
    float ob0 = lane_bcast(oi0, i), ob1 = lane_bcast(oi1, i);
    // solve row i for BOTH batches; wh from LDS (uniform-address ds_read
    // broadcast, static addresses -> pipelines ahead of the serial chain)
    {
      const float* wrow = WHL + i * 47;
      float t00 = (lane == i) ? 1.f : 0.f, t01 = 0.f;
      float t10 = t00, t11 = 0.f;
      int k = 0;
#pragma unroll
      for (; k + 1 < i; k += 2) {
        float w0 = wrow[k], w1 = wrow[k + 1];  // shared LDS broadcasts
        t00 = fmaf(w0, s0[k], t00);
        t01 = fmaf(w1, s0[k + 1], t01);
        t10 = fmaf(w0, s1[k], t10);
        t11 = fmaf(w1, s1[k + 1], t11);
      }
#pragma unroll
      for (; k < i; ++k) {
        float w0 = wrow[k];
        t00 = fmaf(w0, s0[k], t00);
        t10 = fmaf(w0, s1[k], t10);
      }
      s0[i] = (ab0 > 0.f) ? (t00 + t01) : 0.f;
      s1[i] = (ab1 > 0.f) ? (t10 + t11) : 0.f;
    }
    if (i < 47) {
      accA0 += whr[i] * ab0;
      accB0 += whr[i] * ob0;
      accA1 += whr[i] * ab1;
      accB1 += whr[i] * ob1;
    }
  }
  unsigned long long dm0 = __ballot(dl0);
  unsigned long long dm1 = __ballot(dl1);

  size_t base0 = (size_t)b0 * KPAD2;
  size_t base1 = (size_t)b1 * KPAD2;
  if (lane < 48) {
#pragma unroll
    for (int i = 0; i < 48; ++i) {
      if (lane <= i) {
        unsigned short h, l;
        int j = i * (i + 1) / 2 + lane;
        bf16_split(s0[i], h, l);
        Ch[base0 + j] = h;
        Cl[base0 + j] = l;
        bf16_split(s1[i], h, l);
        Ch[base1 + j] = h;
        Cl[base1 + j] = l;
      }
    }
    unsigned short h, l;
    bf16_split(offs0, h, l);
    Ch[base0 + KTRI + lane] = h;
    Cl[base0 + KTRI + lane] = l;
    bf16_split(offs1, h, l);
    Ch[base1 + KTRI + lane] = h;
    Cl[base1 + KTRI + lane] = l;
    mask_out[b0 * 48 + lane] = dl0 ? 1.f : 0.f;
    mask_out[b1 * 48 + lane] = dl1 ? 1.f : 0.f;
  }
  for (int e = KH2 + lane; e < KPAD2; e += 64) {
    Ch[base0 + e] = 0;
    Cl[base0 + e] = 0;
    Ch[base1 + e] = 0;
    Cl[base1 + e] = 0;
  }
}

// ---------------------------------------------------------------------------
// Kernel 1 (merged, 448 blocks x 256 thr):
// blocks [0,192): ghat via MFMA (R19-proven).
// blocks [192,448): seq, 4 waves/block, TWO batch rows per wave; wh staged
//   in a 9KB LDS buffer shared by the block.
// ---------------------------------------------------------------------------
#define GLP 72  // ghat LDS row stride (ushorts)
__global__ __launch_bounds__(256) void k1(const float* __restrict__ W,
                                          const float* __restrict__ Wb0,
                                          const float* __restrict__ x,
                                          const float* __restrict__ bvec,
                                          unsigned short* __restrict__ Gh,
                                          unsigned short* __restrict__ Ch,
                                          unsigned short* __restrict__ Cl,
                                          float* __restrict__ mask_out) {
  const int bid = blockIdx.x;
  const int t = threadIdx.x;
  if (bid < 192) {
    __shared__ unsigned short AhL[64 * GLP], AlL[64 * GLP], BhL[48 * GLP];
    const int i  = bid % 48;
    const int h0 = (bid / 48) * 64;
    const int w = t >> 6;
    const int lane = t & 63;
    const int fr = lane & 15;
    const int fq = lane >> 4;
    const int arow = t >> 4;
    const int ac0 = (t & 15) * 4;
    f32x4 acc[3] = {};
    for (int it = 0; it < 4; ++it) {
      const int dc = it * 64;
      __syncthreads();
#pragma unroll
      for (int p = 0; p < 4; ++p) {
        int r = arow + p * 16;
        const float* src = Wb0 + (size_t)(h0 + r) * LEAF_N + i * 257 + dc + ac0;
        float v0 = src[0], v1 = src[1], v2 = src[2], v3 = src[3];
        ushort4 hh, ll;
        bf16_split(v0, hh.x, ll.x);
        bf16_split(v1, hh.y, ll.y);
        bf16_split(v2, hh.z, ll.z);
        bf16_split(v3, hh.w, ll.w);
        *(ushort4*)&AhL[r * GLP + ac0] = hh;
        *(ushort4*)&AlL[r * GLP + ac0] = ll;
      }
      for (int e = t; e < 48 * 64; e += 256) {
        int r = e >> 6, c = e & 63;
        BhL[r * GLP + c] = bf16_hi(W[r * WROW + dc + c]);
      }
      __syncthreads();
#pragma unroll
      for (int ks = 0; ks < 2; ++ks) {
        int aoff = (w * 16 + fr) * GLP + fq * 8 + ks * 32;
        short8 ah = *(const short8*)&AhL[aoff];
        short8 al = *(const short8*)&AlL[aoff];
#pragma unroll
        for (int nt = 0; nt < 3; ++nt) {
          if (nt * 16 <= i) {  // tri-skip (uniform branch)
            short8 bh = *(const short8*)&BhL[(nt * 16 + fr) * GLP + fq * 8 + ks * 32];
            acc[nt] = __builtin_amdgcn_mfma_f32_16x16x32_bf16(ah, bh, acc[nt], 0, 0, 0);
            acc[nt] = __builtin_amdgcn_mfma_f32_16x16x32_bf16(al, bh, acc[nt], 0, 0, 0);
          }
        }
      }
    }
    const int tb = i * (i + 1) / 2;
#pragma unroll
    for (int nt = 0; nt < 3; ++nt) {
      int k = nt * 16 + fr;
      if (k <= i) {
#pragma unroll
        for (int r = 0; r < 4; ++r) {
          int m = w * 16 + fq * 4 + r;
          Gh[(size_t)(h0 + m) * KPAD2 + tb + k] = bf16_hi(acc[nt][r]);
        }
      }
    }
    if (t < 64)
      Gh[(size_t)(h0 + t) * KPAD2 + KTRI + i] =
          bf16_hi(Wb0[(size_t)(h0 + t) * LEAF_N + i * 257 + 256]);
    if (i == 0) {
      for (int e = t; e < 64 * (KPAD2 - KH2); e += 256) {
        int r = e / (KPAD2 - KH2), c = e - r * (KPAD2 - KH2);
        Gh[(size_t)(h0 + r) * KPAD2 + KH2 + c] = 0;
      }
    }
    return;
  }
  // ---- seq path: stage wh (48x47 = 9KB) once per block ----
  __shared__ float WHL[48 * 47];
  for (int e = t; e < 48 * 47; e += 256) {
    int i = e / 47, k = e - i * 47;
    WHL[e] = W[i * WROW + 256 + k];
  }
  __syncthreads();
  const int wv = (bid - 192) * 4 + (t >> 6);  // 0..1023
  seq_wave2(wv * 2, t & 63, W, WHL, x, bvec, Ch, Cl, mask_out);
}

// ---------------------------------------------------------------------------
// Kernel 2: big GEMM, 2-term bf16 MFMA: acc = Ah*Bh + Al*Bh.
// 4 waves, LDS-staged, LDSP=88. K=1280 split 4x320. XCD-chunk-swizzled.
// ---------------------------------------------------------------------------
#define LDSP 88
__global__ __launch_bounds__(256) void k_gemm_bf16(
    const unsigned short* __restrict__ Ah, const unsigned short* __restrict__ Al,
    const unsigned short* __restrict__ Bh,
    float* __restrict__ part) {
  int flat = blockIdx.x + 32 * blockIdx.y + 128 * blockIdx.z;  // 0..511
  int id = (flat & 7) * 64 + (flat >> 3);                      // XCD chunks
  const int bz = id & 3, by = (id >> 2) & 3, bx = id >> 4;
  const int m0 = bx * 64;
  const int n0 = by * 64;
  const int k0 = bz * 320;
  float* dst = part + (size_t)bz * ((size_t)B_SZ * H_N);
  __shared__ unsigned short AhL[64 * LDSP], AlL[64 * LDSP];
  __shared__ unsigned short BhL[64 * LDSP];
  const int t = threadIdx.x;
  const int lane = t & 63;
  const int w = t >> 6;
  const int fr = lane & 15;
  const int fq = lane >> 4;
  f32x4 acc[4] = {};
  for (int it = 0; it < 5; ++it) {
    int kb = k0 + it * 64;
#pragma unroll
    for (int j = 0; j < 2; ++j) {
      int c = t + j * 256;
      int row = c >> 3, ko = (c & 7) * 8;
      size_t ga = (size_t)(m0 + row) * KPAD2 + kb + ko;
      size_t gb = (size_t)(n0 + row) * KPAD2 + kb + ko;
      *(short8*)&AhL[row * LDSP + ko] = *(const short8*)&Ah[ga];
      *(short8*)&AlL[row * LDSP + ko] = *(const short8*)&Al[ga];
      *(short8*)&BhL[row * LDSP + ko] = *(const short8*)&Bh[gb];
    }
    __syncthreads();
#pragma unroll
    for (int ks = 0; ks < 2; ++ks) {
      int aoff = (w * 16 + fr) * LDSP + fq * 8 + ks * 32;
      short8 ah = *(const short8*)&AhL[aoff];
      short8 al = *(const short8*)&AlL[aoff];
#pragma unroll
      for (int nt = 0; nt < 4; ++nt) {
        int boff = (nt * 16 + fr) * LDSP + fq * 8 + ks * 32;
        short8 bh = *(const short8*)&BhL[boff];
        acc[nt] = __builtin_amdgcn_mfma_f32_16x16x32_bf16(ah, bh, acc[nt], 0, 0, 0);
        acc[nt] = __builtin_amdgcn_mfma_f32_16x16x32_bf16(al, bh, acc[nt], 0, 0, 0);
      }
    }
    __syncthreads();
  }
  // C layout: col = lane&15, row = (lane>>4)*4 + reg  [m89-verified]
  int mrow = m0 + w * 16 + fq * 4;
#pragma unroll
  for (int nt = 0; nt < 4; ++nt) {
    int ncol = n0 + nt * 16 + fr;
#pragma unroll
    for (int r = 0; r < 4; ++r)
      dst[(size_t)(mrow + r) * H_N + ncol] = acc[nt][r];
  }
}

// ---------------------------------------------------------------------------
// Kernel 3: h1 = relu( relu(sum_z part_z + bb0) @ Wb1^T + bb1 ) via bf16
// MFMA; fused reduce+bias+relu+bf16 in A-staging. BM=64 BN=32, 4 waves.
// ---------------------------------------------------------------------------
#define LDSP2 72
__global__ __launch_bounds__(256) void k_gemm2b(const float* __restrict__ part,
                                                const float* __restrict__ bb0,
                                                const float* __restrict__ Bm,
                                                const float* __restrict__ bias,
                                                float* __restrict__ h1) {
  int flat = blockIdx.x + 32 * blockIdx.y;      // 0..255
  int id = (flat & 7) * 32 + (flat >> 3);       // XCD chunks, x slowest
  const int m0 = (id >> 3) * 64;
  const int n0 = (id & 7) * 32;
  const size_t BH = (size_t)B_SZ * H_N;
  __shared__ unsigned short AtL[64 * LDSP2];
  __shared__ unsigned short BtL[32 * LDSP2];
  const int t = threadIdx.x;
  const int lane = t & 63;
  const int w = t >> 6;
  const int fr = lane & 15;
  const int fq = lane >> 4;
  f32x4 acc[2] = {};
  for (int it = 0; it < 4; ++it) {
    int kb = it * 64;
#pragma unroll
    for (int j = 0; j < 4; ++j) {
      int g = t + j * 256;
      int row = g >> 4, c4 = g & 15;
      size_t base = (size_t)(m0 + row) * H_N + kb + c4 * 4;
      float4 v0 = *(const float4*)&part[base];
      float4 v1 = *(const float4*)&part[base + BH];
      float4 v2 = *(const float4*)&part[base + 2 * BH];
      float4 v3 = *(const float4*)&part[base + 3 * BH];
      float4 bi = *(const float4*)&bb0[kb + c4 * 4];
      ushort4 o;
      o.x = bf16_hi(fmaxf(v0.x + v1.x + v2.x + v3.x + bi.x, 0.f));
      o.y = bf16_hi(fmaxf(v0.y + v1.y + v2.y + v3.y + bi.y, 0.f));
      o.z = bf16_hi(fmaxf(v0.z + v1.z + v2.z + v3.z + bi.z, 0.f));
      o.w = bf16_hi(fmaxf(v0.w + v1.w + v2.w + v3.w + bi.w, 0.f));
      *(ushort4*)&AtL[row * LDSP2 + c4 * 4] = o;
    }
#pragma unroll
    for (int j = 0; j < 2; ++j) {
      int g = t + j * 256;
      int row = g >> 4, c4 = g & 15;
      float4 v = *(const float4*)&Bm[(size_t)(n0 + row) * H_N + kb + c4 * 4];
      ushort4 o;
      o.x = bf16_hi(v.x); o.y = bf16_hi(v.y);
      o.z = bf16_hi(v.z); o.w = bf16_hi(v.w);
      *(ushort4*)&BtL[row * LDSP2 + c4 * 4] = o;
    }
    __syncthreads();
#pragma unroll
    for (int ks = 0; ks < 2; ++ks) {
      short8 a8 = *(const short8*)&AtL[(w * 16 + fr) * LDSP2 + fq * 8 + ks * 32];
#pragma unroll
      for (int nt = 0; nt < 2; ++nt) {
        short8 b8 =
            *(const short8*)&BtL[(nt * 16 + fr) * LDSP2 + fq * 8 + ks * 32];
        acc[nt] = __builtin_amdgcn_mfma_f32_16x16x32_bf16(a8, b8, acc[nt], 0, 0, 0);
      }
    }
    __syncthreads();
  }
  int mrow = m0 + w * 16 + fq * 4;
#pragma unroll
  for (int nt = 0; nt < 2; ++nt) {
    int ncol = n0 + nt * 16 + fr;
    float bs = bias[ncol];
#pragma unroll
    for (int r = 0; r < 4; ++r)
      h1[(size_t)(mrow + r) * H_N + ncol] = fmaxf(acc[nt][r] + bs, 0.f);
  }
}

// ---------------------------------------------------------------------------
// Kernel 4: out[b,:] = h1[b,:] @ Wout^T + bout. One wave per batch row.
// ---------------------------------------------------------------------------
__global__ __launch_bounds__(256) void k_out(const float* __restrict__ h1,
                                             const float* __restrict__ Wout,
                                             const float* __restrict__ bout,
                                             float* __restrict__ out) {
  int w = threadIdx.x >> 6, lane = threadIdx.x & 63;
  int b = blockIdx.x * 4 + w;
  const float* hr = h1 + (size_t)b * H_N;
  float h[4];
#pragma unroll
  for (int j = 0; j < 4; ++j) h[j] = hr[lane + 64 * j];
  float acc[10];
#pragma unroll
  for (int o = 0; o < 10; ++o) {
    float s = 0.f;
#pragma unroll
    for (int j = 0; j < 4; ++j) s += h[j] * Wout[o * H_N + lane + 64 * j];
#pragma unroll
    for (int m = 32; m >= 1; m >>= 1) s += __shfl_xor(s, m);
    acc[o] = s;
  }
  if (lane == 0) {
#pragma unroll
    for (int o = 0; o < 10; ++o) out[(size_t)b * O_N + o] = acc[o] + bout[o];
  }
}

// ---------------------------------------------------------------------------
extern "C" void kernel_launch(void* const* d_in, const int* in_sizes, int n_in,
                              void* d_out, int out_size, void* d_ws,
                              size_t ws_size, hipStream_t stream) {
  (void)in_sizes; (void)n_in; (void)out_size; (void)ws_size;
  const float* x    = (const float*)d_in[0];
  const float* W    = (const float*)d_in[1];
  const float* bvec = (const float*)d_in[2];
  const float* Wb0  = (const float*)d_in[3];
  const float* bb0  = (const float*)d_in[4];
  const float* Wb1  = (const float*)d_in[5];
  const float* bb1  = (const float*)d_in[6];
  const float* Wout = (const float*)d_in[7];
  const float* bout = (const float*)d_in[8];

  float* out   = (float*)d_out;     // B*10
  float* masks = out + B_SZ * O_N;  // B*48

  char* wsb = (char*)d_ws;
  unsigned short* Ch = (unsigned short*)wsb;                // B*KPAD2 us
  unsigned short* Cl = Ch + (size_t)B_SZ * KPAD2;
  unsigned short* Gh = Cl + (size_t)B_SZ * KPAD2;           // H*KPAD2 us
  float* part = (float*)(Gh + (size_t)H_N * KPAD2);         // 4*B*H f32
  float* h1 = part + 4 * (size_t)B_SZ * H_N;                // B*H f32
  // total ~22 MB

  k1<<<dim3(448), 256, 0, stream>>>(W, Wb0, x, bvec, Gh, Ch, Cl, masks);
  k_gemm_bf16<<<dim3(32, 4, 4), 256, 0, stream>>>(Ch, Cl, Gh, part);
  k_gemm2b<<<dim3(32, 8), 256, 0, stream>>>(part, bb0, Wb1, bb1, h1);
  k_out<<<dim3(512), 256, 0, stream>>>(h1, Wout, bout, out);
}

// Round 28
// 52.164 us; speedup vs baseline: 4.0674x; 4.0674x over previous
//
#include <hip/hip_runtime.h>

#define B_SZ 2048
#define D_IN 256
#define L_N 48
#define H_N 256
#define O_N 10
#define WROW 303      // D + L - 1
#define LEAF_N 12336  // L*(D+1)
#define KTRI 1176     // 48*49/2 packed lower-tri cols
#define KH2 1224      // KTRI + 48 offs cols
#define KPAD2 1280    // padded K (20 x 64)

using short8 = __attribute__((ext_vector_type(8))) short;
using f32x4  = __attribute__((ext_vector_type(4))) float;

__device__ inline void bf16_split(float v, unsigned short& h, unsigned short& l) {
  unsigned bits = __float_as_uint(v);
  h = (unsigned short)(bits >> 16);
  float hf = __uint_as_float(bits & 0xFFFF0000u);
  float r = v - hf;
  l = (unsigned short)(__float_as_uint(r) >> 16);
}
__device__ inline unsigned short bf16_hi(float v) {
  return (unsigned short)(__float_as_uint(v) >> 16);
}
__device__ __forceinline__ float lane_bcast(float v, int i) {
  return __uint_as_float(__builtin_amdgcn_readlane(__float_as_uint(v), i));
}

// ---------------------------------------------------------------------------
// seq body, TWO BATCHES PER WAVE (proven best, R24/R26): W operands (per-lane
// P rows, whr, solve wrow s_loads) loaded once, used for both batches.
// Recurrence broadcasts via readlane (SALU). Solve keeps wave-uniform GLOBAL
// s_loads: operands live in SGPRs, which is the ONLY transport that keeps the
// 48-deep s0/s1 register arrays resident (LDS/readlane transports -> VGPR
// pressure -> scratch spill; measured 4-5x regressions in R14/R25/R27).
// ---------------------------------------------------------------------------
__device__ __forceinline__ void seq_wave2(int b0, int lane,
                                          const float* __restrict__ W,
                                          const float* __restrict__ x,
                                          const float* __restrict__ bvec,
                                          unsigned short* __restrict__ Ch,
                                          unsigned short* __restrict__ Cl,
                                          float* __restrict__ mask_out) {
  const int b1 = b0 + 1;
  float P0 = 0.f, P1 = 0.f;
  if (lane < 48) {
    const float* xr0 = x + (size_t)b0 * D_IN;
    const float* xr1 = x + (size_t)b1 * D_IN;
    const float* wr = W + lane * WROW;
    float a0 = 0.f, a1 = 0.f, c0 = 0.f, c1 = 0.f;
#pragma unroll 4
    for (int d = 0; d < 256; d += 2) {
      float w0 = wr[d], w1 = wr[d + 1];  // shared per-lane loads
      a0 = fmaf(xr0[d], w0, a0);
      a1 = fmaf(xr0[d + 1], w1, a1);
      c0 = fmaf(xr1[d], w0, c0);
      c1 = fmaf(xr1[d + 1], w1, c1);
    }
    P0 = a0 + a1;
    P1 = c0 + c1;
  }

  float whr[47];
#pragma unroll
  for (int k = 0; k < 47; ++k)
    whr[k] = (lane < 48) ? W[lane * WROW + 256 + k] : 0.f;

  float bv = (lane < 48) ? bvec[lane] : 0.f;
  float Pb0 = P0 + bv, Pb1 = P1 + bv;

  float s0[48], s1[48];
  float accA0 = 0.f, accB0 = 0.f, accA1 = 0.f, accB1 = 0.f;
  float offs0 = 0.f, offs1 = 0.f;
  int dl0 = 0, dl1 = 0;
#pragma unroll
  for (int i = 0; i < 48; ++i) {
    float z0 = Pb0 + accA0, z1 = Pb1 + accA1;
    float u0 = P0 + accB0, u1 = P1 + accB1;
    float ai0 = fmaxf(z0, 0.f), ai1 = fmaxf(z1, 0.f);
    float oi0 = (z0 > 0.f) ? u0 : 0.f, oi1 = (z1 > 0.f) ? u1 : 0.f;
    if (lane == i) {
      dl0 = (z0 > 0.f) ? 1 : 0;
      dl1 = (z1 > 0.f) ? 1 : 0;
      offs0 = ai0 - oi0;
      offs1 = ai1 - oi1;
    }
    float ab0 = lane_bcast(ai0, i), ab1 = lane_bcast(ai1, i);
    float ob0 = lane_bcast(oi0, i), ob1 = lane_bcast(oi1, i);
    // solve row i for BOTH batches, sharing the wave-uniform s_loads
    {
      const float* wrow = W + i * WROW + 256;
      float t00 = (lane == i) ? 1.f : 0.f, t01 = 0.f;
      float t10 = t00, t11 = 0.f;
      int k = 0;
#pragma unroll
      for (; k + 1 < i; k += 2) {
        float w0 = wrow[k], w1 = wrow[k + 1];  // shared s_loads
        t00 = fmaf(w0, s0[k], t00);
        t01 = fmaf(w1, s0[k + 1], t01);
        t10 = fmaf(w0, s1[k], t10);
        t11 = fmaf(w1, s1[k + 1], t11);
      }
#pragma unroll
      for (; k < i; ++k) {
        float w0 = wrow[k];
        t00 = fmaf(w0, s0[k], t00);
        t10 = fmaf(w0, s1[k], t10);
      }
      s0[i] = (ab0 > 0.f) ? (t00 + t01) : 0.f;
      s1[i] = (ab1 > 0.f) ? (t10 + t11) : 0.f;
    }
    if (i < 47) {
      accA0 += whr[i] * ab0;
      accB0 += whr[i] * ob0;
      accA1 += whr[i] * ab1;
      accB1 += whr[i] * ob1;
    }
  }
  unsigned long long dm0 = __ballot(dl0);
  unsigned long long dm1 = __ballot(dl1);

  size_t base0 = (size_t)b0 * KPAD2;
  size_t base1 = (size_t)b1 * KPAD2;
  if (lane < 48) {
#pragma unroll
    for (int i = 0; i < 48; ++i) {
      if (lane <= i) {
        unsigned short h, l;
        int j = i * (i + 1) / 2 + lane;
        bf16_split(s0[i], h, l);
        Ch[base0 + j] = h;
        Cl[base0 + j] = l;
        bf16_split(s1[i], h, l);
        Ch[base1 + j] = h;
        Cl[base1 + j] = l;
      }
    }
    unsigned short h, l;
    bf16_split(offs0, h, l);
    Ch[base0 + KTRI + lane] = h;
    Cl[base0 + KTRI + lane] = l;
    bf16_split(offs1, h, l);
    Ch[base1 + KTRI + lane] = h;
    Cl[base1 + KTRI + lane] = l;
    mask_out[b0 * 48 + lane] = dl0 ? 1.f : 0.f;
    mask_out[b1 * 48 + lane] = dl1 ? 1.f : 0.f;
  }
  for (int e = KH2 + lane; e < KPAD2; e += 64) {
    Ch[base0 + e] = 0;
    Cl[base0 + e] = 0;
    Ch[base1 + e] = 0;
    Cl[base1 + e] = 0;
  }
}

// ---------------------------------------------------------------------------
// Kernel 1 (merged, 448 blocks x 256 thr):
// blocks [0,192): ghat via MFMA (R19-proven).
// blocks [192,448): seq, 4 waves/block, TWO batch rows per wave.
// ---------------------------------------------------------------------------
#define GLP 72  // ghat LDS row stride (ushorts)
__global__ __launch_bounds__(256) void k1(const float* __restrict__ W,
                                          const float* __restrict__ Wb0,
                                          const float* __restrict__ x,
                                          const float* __restrict__ bvec,
                                          unsigned short* __restrict__ Gh,
                                          unsigned short* __restrict__ Ch,
                                          unsigned short* __restrict__ Cl,
                                          float* __restrict__ mask_out) {
  const int bid = blockIdx.x;
  const int t = threadIdx.x;
  if (bid < 192) {
    __shared__ unsigned short AhL[64 * GLP], AlL[64 * GLP], BhL[48 * GLP];
    const int i  = bid % 48;
    const int h0 = (bid / 48) * 64;
    const int w = t >> 6;
    const int lane = t & 63;
    const int fr = lane & 15;
    const int fq = lane >> 4;
    const int arow = t >> 4;
    const int ac0 = (t & 15) * 4;
    f32x4 acc[3] = {};
    for (int it = 0; it < 4; ++it) {
      const int dc = it * 64;
      __syncthreads();
#pragma unroll
      for (int p = 0; p < 4; ++p) {
        int r = arow + p * 16;
        const float* src = Wb0 + (size_t)(h0 + r) * LEAF_N + i * 257 + dc + ac0;
        float v0 = src[0], v1 = src[1], v2 = src[2], v3 = src[3];
        ushort4 hh, ll;
        bf16_split(v0, hh.x, ll.x);
        bf16_split(v1, hh.y, ll.y);
        bf16_split(v2, hh.z, ll.z);
        bf16_split(v3, hh.w, ll.w);
        *(ushort4*)&AhL[r * GLP + ac0] = hh;
        *(ushort4*)&AlL[r * GLP + ac0] = ll;
      }
      for (int e = t; e < 48 * 64; e += 256) {
        int r = e >> 6, c = e & 63;
        BhL[r * GLP + c] = bf16_hi(W[r * WROW + dc + c]);
      }
      __syncthreads();
#pragma unroll
      for (int ks = 0; ks < 2; ++ks) {
        int aoff = (w * 16 + fr) * GLP + fq * 8 + ks * 32;
        short8 ah = *(const short8*)&AhL[aoff];
        short8 al = *(const short8*)&AlL[aoff];
#pragma unroll
        for (int nt = 0; nt < 3; ++nt) {
          if (nt * 16 <= i) {  // tri-skip (uniform branch)
            short8 bh = *(const short8*)&BhL[(nt * 16 + fr) * GLP + fq * 8 + ks * 32];
            acc[nt] = __builtin_amdgcn_mfma_f32_16x16x32_bf16(ah, bh, acc[nt], 0, 0, 0);
            acc[nt] = __builtin_amdgcn_mfma_f32_16x16x32_bf16(al, bh, acc[nt], 0, 0, 0);
          }
        }
      }
    }
    const int tb = i * (i + 1) / 2;
#pragma unroll
    for (int nt = 0; nt < 3; ++nt) {
      int k = nt * 16 + fr;
      if (k <= i) {
#pragma unroll
        for (int r = 0; r < 4; ++r) {
          int m = w * 16 + fq * 4 + r;
          Gh[(size_t)(h0 + m) * KPAD2 + tb + k] = bf16_hi(acc[nt][r]);
        }
      }
    }
    if (t < 64)
      Gh[(size_t)(h0 + t) * KPAD2 + KTRI + i] =
          bf16_hi(Wb0[(size_t)(h0 + t) * LEAF_N + i * 257 + 256]);
    if (i == 0) {
      for (int e = t; e < 64 * (KPAD2 - KH2); e += 256) {
        int r = e / (KPAD2 - KH2), c = e - r * (KPAD2 - KH2);
        Gh[(size_t)(h0 + r) * KPAD2 + KH2 + c] = 0;
      }
    }
    return;
  }
  const int wv = (bid - 192) * 4 + (t >> 6);  // 0..1023
  seq_wave2(wv * 2, t & 63, W, x, bvec, Ch, Cl, mask_out);
}

// ---------------------------------------------------------------------------
// Kernel 2: big GEMM, 2-term bf16 MFMA: acc = Ah*Bh + Al*Bh.
// 4 waves, LDS-staged, LDSP=88. K=1280 split 4x320. XCD-chunk-swizzled.
// ---------------------------------------------------------------------------
#define LDSP 88
__global__ __launch_bounds__(256) void k_gemm_bf16(
    const unsigned short* __restrict__ Ah, const unsigned short* __restrict__ Al,
    const unsigned short* __restrict__ Bh,
    float* __restrict__ part) {
  int flat = blockIdx.x + 32 * blockIdx.y + 128 * blockIdx.z;  // 0..511
  int id = (flat & 7) * 64 + (flat >> 3);                      // XCD chunks
  const int bz = id & 3, by = (id >> 2) & 3, bx = id >> 4;
  const int m0 = bx * 64;
  const int n0 = by * 64;
  const int k0 = bz * 320;
  float* dst = part + (size_t)bz * ((size_t)B_SZ * H_N);
  __shared__ unsigned short AhL[64 * LDSP], AlL[64 * LDSP];
  __shared__ unsigned short BhL[64 * LDSP];
  const int t = threadIdx.x;
  const int lane = t & 63;
  const int w = t >> 6;
  const int fr = lane & 15;
  const int fq = lane >> 4;
  f32x4 acc[4] = {};
  for (int it = 0; it < 5; ++it) {
    int kb = k0 + it * 64;
#pragma unroll
    for (int j = 0; j < 2; ++j) {
      int c = t + j * 256;
      int row = c >> 3, ko = (c & 7) * 8;
      size_t ga = (size_t)(m0 + row) * KPAD2 + kb + ko;
      size_t gb = (size_t)(n0 + row) * KPAD2 + kb + ko;
      *(short8*)&AhL[row * LDSP + ko] = *(const short8*)&Ah[ga];
      *(short8*)&AlL[row * LDSP + ko] = *(const short8*)&Al[ga];
      *(short8*)&BhL[row * LDSP + ko] = *(const short8*)&Bh[gb];
    }
    __syncthreads();
#pragma unroll
    for (int ks = 0; ks < 2; ++ks) {
      int aoff = (w * 16 + fr) * LDSP + fq * 8 + ks * 32;
      short8 ah = *(const short8*)&AhL[aoff];
      short8 al = *(const short8*)&AlL[aoff];
#pragma unroll
      for (int nt = 0; nt < 4; ++nt) {
        int boff = (nt * 16 + fr) * LDSP + fq * 8 + ks * 32;
        short8 bh = *(const short8*)&BhL[boff];
        acc[nt] = __builtin_amdgcn_mfma_f32_16x16x32_bf16(ah, bh, acc[nt], 0, 0, 0);
        acc[nt] = __builtin_amdgcn_mfma_f32_16x16x32_bf16(al, bh, acc[nt], 0, 0, 0);
      }
    }
    __syncthreads();
  }
  // C layout: col = lane&15, row = (lane>>4)*4 + reg  [m89-verified]
  int mrow = m0 + w * 16 + fq * 4;
#pragma unroll
  for (int nt = 0; nt < 4; ++nt) {
    int ncol = n0 + nt * 16 + fr;
#pragma unroll
    for (int r = 0; r < 4; ++r)
      dst[(size_t)(mrow + r) * H_N + ncol] = acc[nt][r];
  }
}

// ---------------------------------------------------------------------------
// Kernel 3: h1 = relu( relu(sum_z part_z + bb0) @ Wb1^T + bb1 ) via bf16
// MFMA; fused reduce+bias+relu+bf16 in A-staging. BM=64 BN=32, 4 waves.
// ---------------------------------------------------------------------------
#define LDSP2 72
__global__ __launch_bounds__(256) void k_gemm2b(const float* __restrict__ part,
                                                const float* __restrict__ bb0,
                                                const float* __restrict__ Bm,
                                                const float* __restrict__ bias,
                                                float* __restrict__ h1) {
  int flat = blockIdx.x + 32 * blockIdx.y;      // 0..255
  int id = (flat & 7) * 32 + (flat >> 3);       // XCD chunks, x slowest
  const int m0 = (id >> 3) * 64;
  const int n0 = (id & 7) * 32;
  const size_t BH = (size_t)B_SZ * H_N;
  __shared__ unsigned short AtL[64 * LDSP2];
  __shared__ unsigned short BtL[32 * LDSP2];
  const int t = threadIdx.x;
  const int lane = t & 63;
  const int w = t >> 6;
  const int fr = lane & 15;
  const int fq = lane >> 4;
  f32x4 acc[2] = {};
  for (int it = 0; it < 4; ++it) {
    int kb = it * 64;
#pragma unroll
    for (int j = 0; j < 4; ++j) {
      int g = t + j * 256;
      int row = g >> 4, c4 = g & 15;
      size_t base = (size_t)(m0 + row) * H_N + kb + c4 * 4;
      float4 v0 = *(const float4*)&part[base];
      float4 v1 = *(const float4*)&part[base + BH];
      float4 v2 = *(const float4*)&part[base + 2 * BH];
      float4 v3 = *(const float4*)&part[base + 3 * BH];
      float4 bi = *(const float4*)&bb0[kb + c4 * 4];
      ushort4 o;
      o.x = bf16_hi(fmaxf(v0.x + v1.x + v2.x + v3.x + bi.x, 0.f));
      o.y = bf16_hi(fmaxf(v0.y + v1.y + v2.y + v3.y + bi.y, 0.f));
      o.z = bf16_hi(fmaxf(v0.z + v1.z + v2.z + v3.z + bi.z, 0.f));
      o.w = bf16_hi(fmaxf(v0.w + v1.w + v2.w + v3.w + bi.w, 0.f));
      *(ushort4*)&AtL[row * LDSP2 + c4 * 4] = o;
    }
#pragma unroll
    for (int j = 0; j < 2; ++j) {
      int g = t + j * 256;
      int row = g >> 4, c4 = g & 15;
      float4 v = *(const float4*)&Bm[(size_t)(n0 + row) * H_N + kb + c4 * 4];
      ushort4 o;
      o.x = bf16_hi(v.x); o.y = bf16_hi(v.y);
      o.z = bf16_hi(v.z); o.w = bf16_hi(v.w);
      *(ushort4*)&BtL[row * LDSP2 + c4 * 4] = o;
    }
    __syncthreads();
#pragma unroll
    for (int ks = 0; ks < 2; ++ks) {
      short8 a8 = *(const short8*)&AtL[(w * 16 + fr) * LDSP2 + fq * 8 + ks * 32];
#pragma unroll
      for (int nt = 0; nt < 2; ++nt) {
        short8 b8 =
            *(const short8*)&BtL[(nt * 16 + fr) * LDSP2 + fq * 8 + ks * 32];
        acc[nt] = __builtin_amdgcn_mfma_f32_16x16x32_bf16(a8, b8, acc[nt], 0, 0, 0);
      }
    }
    __syncthreads();
  }
  int mrow = m0 + w * 16 + fq * 4;
#pragma unroll
  for (int nt = 0; nt < 2; ++nt) {
    int ncol = n0 + nt * 16 + fr;
    float bs = bias[ncol];
#pragma unroll
    for (int r = 0; r < 4; ++r)
      h1[(size_t)(mrow + r) * H_N + ncol] = fmaxf(acc[nt][r] + bs, 0.f);
  }
}

// ---------------------------------------------------------------------------
// Kernel 4: out[b,:] = h1[b,:] @ Wout^T + bout. One wave per batch row.
// ---------------------------------------------------------------------------
__global__ __launch_bounds__(256) void k_out(const float* __restrict__ h1,
                                             const float* __restrict__ Wout,
                                             const float* __restrict__ bout,
                                             float* __restrict__ out) {
  int w = threadIdx.x >> 6, lane = threadIdx.x & 63;
  int b = blockIdx.x * 4 + w;
  const float* hr = h1 + (size_t)b * H_N;
  float h[4];
#pragma unroll
  for (int j = 0; j < 4; ++j) h[j] = hr[lane + 64 * j];
  float acc[10];
#pragma unroll
  for (int o = 0; o < 10; ++o) {
    float s = 0.f;
#pragma unroll
    for (int j = 0; j < 4; ++j) s += h[j] * Wout[o * H_N + lane + 64 * j];
#pragma unroll
    for (int m = 32; m >= 1; m >>= 1) s += __shfl_xor(s, m);
    acc[o] = s;
  }
  if (lane == 0) {
#pragma unroll
    for (int o = 0; o < 10; ++o) out[(size_t)b * O_N + o] = acc[o] + bout[o];
  }
}

// ---------------------------------------------------------------------------
extern "C" void kernel_launch(void* const* d_in, const int* in_sizes, int n_in,
                              void* d_out, int out_size, void* d_ws,
                              size_t ws_size, hipStream_t stream) {
  (void)in_sizes; (void)n_in; (void)out_size; (void)ws_size;
  const float* x    = (const float*)d_in[0];
  const float* W    = (const float*)d_in[1];
  const float* bvec = (const float*)d_in[2];
  const float* Wb0  = (const float*)d_in[3];
  const float* bb0  = (const float*)d_in[4];
  const float* Wb1  = (const float*)d_in[5];
  const float* bb1  = (const float*)d_in[6];
  const float* Wout = (const float*)d_in[7];
  const float* bout = (const float*)d_in[8];

  float* out   = (float*)d_out;     // B*10
  float* masks = out + B_SZ * O_N;  // B*48

  char* wsb = (char*)d_ws;
  unsigned short* Ch = (unsigned short*)wsb;                // B*KPAD2 us
  unsigned short* Cl = Ch + (size_t)B_SZ * KPAD2;
  unsigned short* Gh = Cl + (size_t)B_SZ * KPAD2;           // H*KPAD2 us
  float* part = (float*)(Gh + (size_t)H_N * KPAD2);         // 4*B*H f32
  float* h1 = part + 4 * (size_t)B_SZ * H_N;                // B*H f32
  // total ~22 MB

  k1<<<dim3(448), 256, 0, stream>>>(W, Wb0, x, bvec, Gh, Ch, Cl, masks);
  k_gemm_bf16<<<dim3(32, 4, 4), 256, 0, stream>>>(Ch, Cl, Gh, part);
  k_gemm2b<<<dim3(32, 8), 256, 0, stream>>>(part, bb0, Wb1, bb1, h1);
  k_out<<<dim3(512), 256, 0, stream>>>(h1, Wout, bout, out);
}